// Round 9
// baseline (294.771 us; speedup 1.0000x reference)
//
#include <hip/hip_runtime.h>
#include <hip/hip_bf16.h>

// CausalSelfAttention on MI355X (gfx950).
// B=2, S=2048, HIDDEN=2048, H=16 heads, D=128, Hkv=4 (GQA groups=4).
// Round 17:
//   (a) QKV projection moved from 256^2 8-phase (192 blocks = 75% fill, 1
//       blk/CU @128KB LDS) to the PROVEN-faster 128x256 2-phase kernel (R15/R16
//       A/B: Wo gained ~13us with it). Grid (12,32)=384 blocks. gemm_bf16_256
//       deleted.
//   (b) vt_from_qkv vectorized: 64x64 tiles, short8 16B global loads+stores
//       both sides (was 2048 blocks of scalar u16), LDS u16 scatter transpose.
//   flash_attn and prep byte-identical to R16 (controls).
//
// MFMA layouts (HW-verified per guide m89/m91/m120):
//   A frag: A[m=lane&15][k=(lane>>4)*8 + j], j=0..7  (16B contiguous in K)
//   B frag: B^T stored [n][k], same addressing as A
//   C/D   : col=lane&15, row=(lane>>4)*4 + reg

typedef unsigned short u16;
typedef unsigned long long u64;
typedef __attribute__((ext_vector_type(8))) short short8;   // 8 x bf16 (4 VGPRs)
typedef __attribute__((ext_vector_type(4))) float f32x4;
typedef __attribute__((ext_vector_type(4))) unsigned uint4v;

#define BATCH 2
#define SEQ 2048
#define HIDDEN 2048
#define NH 16
#define NKV 4
#define HD 128
#define QKV_N 3072   // 2048 q + 512 k + 512 v
#define MROWS 4096   // BATCH*SEQ

__device__ inline u16 f2bf(float f) {
    __hip_bfloat16 h = __float2bfloat16(f);
    return __builtin_bit_cast(u16, h);
}

// async global->LDS, 16B per lane; lds base must be wave-uniform (HW adds lane*16)
__device__ inline void async_copy16(const u16* g, u16* lds_base) {
    __builtin_amdgcn_global_load_lds(
        (const __attribute__((address_space(1))) void*)g,
        (__attribute__((address_space(3))) void*)lds_base, 16, 0, 0);
}

// ---------------- fused prep: convert + 4 transposes + bias + mask ----------------
#define PREP_CONV   4096
#define PREP_WQ     (PREP_CONV + 1024)
#define PREP_WK     (PREP_WQ + 256)
#define PREP_WV     (PREP_WK + 256)
#define PREP_WO     (PREP_WV + 1024)
#define PREP_BIAS   (PREP_WO + 12)
#define PREP_TOTAL  (PREP_BIAS + 1)

// src[K=2048][N] fp32 -> dst[N][2048] bf16, one 64x64 tile per block.
__device__ inline void prep_transpose64(const float* __restrict__ src, u16* __restrict__ dst,
                                        int N, int sub, float (*tl)[69]) {
    int nx = N >> 6;
    int bx = sub % nx, by = sub / nx;
    int n0 = bx * 64, k0 = by * 64;
    int t = threadIdx.x;
    int rr = t >> 4, cc = (t & 15) * 4;       // read rows k0+rr+16j, cols n0+cc..+3
#pragma unroll
    for (int j = 0; j < 4; ++j) {
        float4 v = *(const float4*)(src + (size_t)(k0 + rr + 16 * j) * N + n0 + cc);
        int k = rr + 16 * j;
        tl[cc + 0][k] = v.x;
        tl[cc + 1][k] = v.y;
        tl[cc + 2][k] = v.z;
        tl[cc + 3][k] = v.w;
    }
    __syncthreads();
    int n = t >> 2;                            // write dst row n0+n, 2 chunks of 8 k
#pragma unroll
    for (int j = 0; j < 2; ++j) {
        int kk = (t & 3) * 8 + 32 * j;
        short8 o8;
#pragma unroll
        for (int i = 0; i < 8; ++i) o8[i] = (short)f2bf(tl[n][kk + i]);
        *(short8*)(dst + (size_t)(n0 + n) * HIDDEN + k0 + kk) = o8;
    }
}

__global__ __launch_bounds__(256)
void prep(const float* __restrict__ hidden, u16* __restrict__ xb,
          const float* __restrict__ Wq, const float* __restrict__ Wk,
          const float* __restrict__ Wv, const float* __restrict__ Wo,
          u16* __restrict__ wqkvT, u16* __restrict__ woT,
          const float* __restrict__ bq, const float* __restrict__ bk,
          const float* __restrict__ bv, float* __restrict__ bqkv,
          const int* __restrict__ am, u64* __restrict__ mp) {
    __shared__ float tl[64][69];
    int bid = blockIdx.x;
    if (bid < PREP_CONV) {
        int i = (bid * 256 + threadIdx.x) * 8;
        float4 v0 = *(const float4*)(hidden + i);
        float4 v1 = *(const float4*)(hidden + i + 4);
        short8 o8;
        o8[0] = (short)f2bf(v0.x); o8[1] = (short)f2bf(v0.y);
        o8[2] = (short)f2bf(v0.z); o8[3] = (short)f2bf(v0.w);
        o8[4] = (short)f2bf(v1.x); o8[5] = (short)f2bf(v1.y);
        o8[6] = (short)f2bf(v1.z); o8[7] = (short)f2bf(v1.w);
        *(short8*)(xb + i) = o8;
    } else if (bid < PREP_WQ) {
        prep_transpose64(Wq, wqkvT, 2048, bid - PREP_CONV, tl);
    } else if (bid < PREP_WK) {
        prep_transpose64(Wk, wqkvT + (size_t)2048 * HIDDEN, 512, bid - PREP_WQ, tl);
    } else if (bid < PREP_WV) {
        prep_transpose64(Wv, wqkvT + (size_t)2560 * HIDDEN, 512, bid - PREP_WK, tl);
    } else if (bid < PREP_WO) {
        prep_transpose64(Wo, woT, 2048, bid - PREP_WV, tl);
    } else if (bid < PREP_BIAS) {
        int i = (bid - PREP_WO) * 256 + threadIdx.x;
        if (i < QKV_N)
            bqkv[i] = (i < 2048) ? bq[i] : ((i < 2560) ? bk[i - 2048] : bv[i - 2560]);
    } else {
        int i = threadIdx.x;   // word index, 64 total
        if (i < BATCH * SEQ / 64) {
            const int* a = am + i * 64;
            u64 m = 0;
#pragma unroll
            for (int j = 0; j < 64; j += 4) {
                int4 v = *(const int4*)(a + j);
                m |= ((u64)(v.x != 0) << j) | ((u64)(v.y != 0) << (j + 1)) |
                     ((u64)(v.z != 0) << (j + 2)) | ((u64)(v.w != 0) << (j + 3));
            }
            mp[i] = m;
        }
    }
}

// ---------------- V^T extraction from qkv buffer (vectorized 64x64) ----------------
// qkv row stride 3072; v at col 2560 + kvh*128 + d. VT layout: [b][kvh][d=128][s=2048]
// grid (SEQ/64, HD/64, BATCH*NKV), 256 threads. short8 16B global on both sides;
// LDS u16 scatter (4-way write conflict on the scatter = 1.58x, negligible here).
__global__ __launch_bounds__(256)
void vt_from_qkv(const u16* __restrict__ qkv, u16* __restrict__ vt) {
    __shared__ u16 tl[64][72];   // [d][s], row stride 144 B (16B-aligned)
    int b = blockIdx.z >> 2, kvh = blockIdx.z & 3;
    int s0 = blockIdx.x * 64, d0 = blockIdx.y * 64;
    int t = threadIdx.x;
    int sr = t >> 2, ch = t & 3;   // row within tile, chunk index
#pragma unroll
    for (int j = 0; j < 2; ++j) {
        int dd = (ch + 4 * j) * 8;
        short8 v = *(const short8*)(qkv + (size_t)(b * SEQ + s0 + sr) * QKV_N +
                                    2560 + kvh * HD + d0 + dd);
#pragma unroll
        for (int i = 0; i < 8; ++i) tl[dd + i][sr] = (u16)v[i];
    }
    __syncthreads();
#pragma unroll
    for (int j = 0; j < 2; ++j) {
        int ss = (ch + 4 * j) * 8;
        short8 o;
#pragma unroll
        for (int i = 0; i < 8; ++i) o[i] = (short)tl[sr][ss + i];
        *(short8*)(vt + (size_t)((b * NKV + kvh) * HD + d0 + sr) * SEQ + s0 + ss) = o;
    }
}

// ---------------- bf16 GEMM, 128x256 2-phase counted-vmcnt (both projections) -----
// BM=128, BN=256, BK=64. 512 thr = 8 waves (2M x 4N), per-wave 64x64 out.
// LDS 96 KiB (sA 32 + sB 64), 1 block/CU. QKV: grid (12,32)=384 blocks;
// Wo: grid (8,32)=256 blocks = 100% fill.
// Ledger (2 instr per half-tile stage): prologue A0,Bh0,Bh1 -> vmcnt(2) (A0,Bh0
// done, Bh1 in flight). ph0: read A(8)+Bh0(4); stage A(t+1)+Bh0(t+1); 16 MFMA;
// vmcnt(4) completes Bh1(t) for ph1. ph1: read Bh1(4); stage Bh1(t+1); 16 MFMA;
// vmcnt(2) completes A(t+1),Bh0(t+1) for next ph0; leaves Bh1(t+1)=2 -> steady.
// vmcnt(0) only at peeled last tile.
template <bool OUT_BF16>
__global__ __launch_bounds__(512, 2)
void gemm_bf16_128x256(const u16* __restrict__ A, const u16* __restrict__ BT,
                       const float* __restrict__ bias, void* __restrict__ outp,
                       int M, int N, int K) {
    __shared__ __align__(16) u16 sA[2][128][64];   // 32 KiB
    __shared__ __align__(16) u16 sB[2][256][64];   // 64 KiB
    const int t = threadIdx.x, w = t >> 6, lane = t & 63;
    const int quad = lane >> 4, l16 = lane & 15;
    const int wm = w >> 2, wn = w & 3;
    const int bm0 = blockIdx.y * 128, bn0 = blockIdx.x * 256;
    const int lrow = lane >> 3;
    const int lchk = (lane & 7) ^ lrow;
    const int NT = K >> 6;

    f32x4 acc[4][4];
#pragma unroll
    for (int i = 0; i < 4; i++)
#pragma unroll
        for (int j = 0; j < 4; j++) acc[i][j] = (f32x4){0.f, 0.f, 0.f, 0.f};

    const u16* gA = A + (size_t)bm0 * K;
    const u16* gB = BT + (size_t)bn0 * K;

    auto stageA = [&](int buf, int k0) {
#pragma unroll
        for (int l = 0; l < 2; ++l) {
            int rb = w * 16 + l * 8;
            async_copy16(gA + (size_t)(rb + lrow) * K + k0 + lchk * 8, &sA[buf][rb][0]);
        }
    };
    auto stageB = [&](int buf, int h, int k0) {
#pragma unroll
        for (int l = 0; l < 2; ++l) {
            int rb = h * 128 + w * 16 + l * 8;
            async_copy16(gB + (size_t)(rb + lrow) * K + k0 + lchk * 8, &sB[buf][rb][0]);
        }
    };
    auto readA = [&](short8 (&aq)[4][2], int buf) {
#pragma unroll
        for (int mt = 0; mt < 4; ++mt) {
            int row = wm * 64 + mt * 16 + l16;
            int swz = row & 7;
#pragma unroll
            for (int kk = 0; kk < 2; ++kk) {
                int chunk = ((kk << 2) | quad) ^ swz;
                aq[mt][kk] = *(const short8*)(&sA[buf][row][chunk << 3]);
            }
        }
    };
    auto readB = [&](short8 (&bq)[2][2], int buf, int nh) {
#pragma unroll
        for (int nt = 0; nt < 2; ++nt) {
            int row = nh * 128 + nt * 64 + wn * 16 + l16;
            int swz = row & 7;
#pragma unroll
            for (int kk = 0; kk < 2; ++kk) {
                int chunk = ((kk << 2) | quad) ^ swz;
                bq[nt][kk] = *(const short8*)(&sB[buf][row][chunk << 3]);
            }
        }
    };
    auto mmaH = [&](short8 (&aq)[4][2], short8 (&bq)[2][2], int nh) {
        __builtin_amdgcn_s_setprio(1);
#pragma unroll
        for (int mt = 0; mt < 4; ++mt)
#pragma unroll
            for (int nt = 0; nt < 2; ++nt)
#pragma unroll
                for (int kk = 0; kk < 2; ++kk)
                    acc[mt][nh * 2 + nt] = __builtin_amdgcn_mfma_f32_16x16x32_bf16(
                        aq[mt][kk], bq[nt][kk], acc[mt][nh * 2 + nt], 0, 0, 0);
        __builtin_amdgcn_s_setprio(0);
    };

    // prologue: A(0), Bh0(0), Bh1(0)
    stageA(0, 0); stageB(0, 0, 0); stageB(0, 1, 0);
    asm volatile("s_waitcnt vmcnt(2)" ::: "memory");
    __builtin_amdgcn_s_barrier();

    short8 aq[4][2], b0[2][2], b1[2][2];
    for (int tt = 0; tt < NT - 1; ++tt) {
        const int cur = tt & 1, nxt = cur ^ 1, k1 = (tt + 1) << 6;
        // ph0: B-half 0
        readA(aq, cur); readB(b0, cur, 0);
        stageA(nxt, k1); stageB(nxt, 0, k1);
        mmaH(aq, b0, 0);
        asm volatile("s_waitcnt vmcnt(4)" ::: "memory");
        __builtin_amdgcn_s_barrier();
        // ph1: B-half 1
        readB(b1, cur, 1);
        stageB(nxt, 1, k1);
        mmaH(aq, b1, 1);
        asm volatile("s_waitcnt vmcnt(2)" ::: "memory");
        __builtin_amdgcn_s_barrier();
    }
    // peeled last tile
    asm volatile("s_waitcnt vmcnt(0)" ::: "memory");
    __builtin_amdgcn_s_barrier();
    {
        const int cur = (NT - 1) & 1;
        readA(aq, cur); readB(b0, cur, 0);
        mmaH(aq, b0, 0);
        readB(b1, cur, 1);
        mmaH(aq, b1, 1);
    }

    // epilogue (+bias)
#pragma unroll
    for (int j = 0; j < 4; ++j) {
        int col = bn0 + j * 64 + wn * 16 + l16;
        float bcol = bias[col];
#pragma unroll
        for (int mt = 0; mt < 4; ++mt) {
#pragma unroll
            for (int r = 0; r < 4; ++r) {
                int row = bm0 + wm * 64 + mt * 16 + quad * 4 + r;
                float v = acc[mt][j][r] + bcol;
                if constexpr (OUT_BF16)
                    ((u16*)outp)[(size_t)row * N + col] = f2bf(v);
                else
                    ((float*)outp)[(size_t)row * N + col] = v;
            }
        }
    }
}

// ---------------- flash attention (causal, GQA), fixed-shift softmax --------
// (byte-identical to R14/R16: padded Ks[64][136]/Vs[128][72]; mask fast path; T12)
__global__ __launch_bounds__(512, 4)
void flash_attn(const u16* __restrict__ qkv, const u16* __restrict__ vt,
                const u64* __restrict__ mp, u16* __restrict__ attn) {
    __shared__ __align__(16) u16 Ks[64][136];   // 128 + 8 pad (natural key order)
    __shared__ __align__(16) u16 Vs[128][72];   // 64 + 8 pad
    int t = threadIdx.x, w = t >> 6, lane = t & 63, quad = lane >> 4, l16 = lane & 15;
    int bx = blockIdx.x, b = blockIdx.z;
    int qt = b ? ((int)gridDim.x - 1 - bx) : bx;    // complementary pairing
    int h = blockIdx.y, kvh = h >> 2;
    int q_row0 = qt * 128 + w * 16;

    const u16* qrow = qkv + (size_t)(b * SEQ + q_row0 + l16) * QKV_N + h * HD;
    short8 qf[4];
#pragma unroll
    for (int c = 0; c < 4; c++) qf[c] = *(const short8*)(qrow + c * 32 + quad * 8);

    f32x4 o[8];
#pragma unroll
    for (int dt = 0; dt < 8; dt++) o[dt] = (f32x4){0.f, 0.f, 0.f, 0.f};
    float lpart = 0.f;   // per-lane partial row-sum for q-row l16

    const float scale2 = 0.12751743f;   // (1/sqrt(128)) * log2(e)
    const float C2 = 14.4269504f;       // 10 * log2(e)

    const u16* kgb = qkv + (size_t)(b * SEQ) * QKV_N + 2048 + kvh * HD;
    const u16* vgb = vt + (size_t)((b * NKV + kvh) * HD) * SEQ;
    const u64* mpb = mp + b * (SEQ / 64);

    int kr = t >> 4, kc = (t & 15) * 8;   // K: 16 chunks per 128-col row
    int vr = t >> 3, vc = (t & 7) * 8;    // V: 8 chunks per 64-col row
    int kb_end = (qt + 1) * 128;

    short8 k0p, k1p, v0p, v1p;
    {
        k0p = *(const short8*)(kgb + (size_t)kr * QKV_N + kc);
        k1p = *(const short8*)(kgb + (size_t)(kr + 32) * QKV_N + kc);
        v0p = *(const short8*)(vgb + (size_t)vr * SEQ + vc);
        v1p = *(const short8*)(vgb + (size_t)(vr + 64) * SEQ + vc);
    }

    for (int kb = 0; kb < kb_end; kb += 64) {
        __syncthreads();  // previous iter's LDS reads done
        *(short8*)(&Ks[kr][kc]) = k0p;
        *(short8*)(&Ks[kr + 32][kc]) = k1p;
        *(short8*)(&Vs[vr][vc]) = v0p;
        *(short8*)(&Vs[vr + 64][vc]) = v1p;
        __syncthreads();
        if (kb + 64 < kb_end) {  // prefetch next tile during compute (T14 issue-early)
            const u16* kg = kgb + (size_t)(kb + 64) * QKV_N;
            const u16* vg = vgb + kb + 64;
            k0p = *(const short8*)(kg + (size_t)kr * QKV_N + kc);
            k1p = *(const short8*)(kg + (size_t)(kr + 32) * QKV_N + kc);
            v0p = *(const short8*)(vg + (size_t)vr * SEQ + vc);
            v1p = *(const short8*)(vg + (size_t)(vr + 64) * SEQ + vc);
        }
        if (kb > q_row0 + 15) continue;  // wave-uniform: no keys for this wave's rows

        u64 mk = mpb[kb >> 6];   // wave-uniform mask bits for keys kb..kb+63

        // ---- scores (swapped): sc[nt][r] = S[key=kb+nt*16+quad*4+r][qrow=l16]
        f32x4 sc[4];
#pragma unroll
        for (int nt = 0; nt < 4; nt++) sc[nt] = (f32x4){0.f, 0.f, 0.f, 0.f};
        __builtin_amdgcn_s_setprio(1);
#pragma unroll
        for (int c = 0; c < 4; c++) {
#pragma unroll
            for (int nt = 0; nt < 4; nt++) {
                short8 kf = *(const short8*)(&Ks[nt * 16 + l16][c * 32 + quad * 8]);
                sc[nt] = __builtin_amdgcn_mfma_f32_16x16x32_bf16(kf, qf[c], sc[nt], 0, 0, 0);
            }
        }
        __builtin_amdgcn_s_setprio(0);

        // early V fragments (keys 0..31, dims 0..63): independent of softmax
        short8 vf0a[4];
#pragma unroll
        for (int dt = 0; dt < 4; dt++)
            vf0a[dt] = *(const short8*)(&Vs[dt * 16 + l16][quad * 8]);

        // ---- fixed-shift exp; fast path for fully-valid tiles (wave-uniform)
        float p[4][4];
        if (mk == ~0ull && kb + 63 <= q_row0) {
#pragma unroll
            for (int nt = 0; nt < 4; nt++)
#pragma unroll
                for (int r = 0; r < 4; r++)
                    p[nt][r] = __builtin_exp2f(__builtin_fmaf(sc[nt][r], scale2, -C2));
        } else {
            int limit = q_row0 + l16 - kb;   // keep iff bp <= limit (causal)
#pragma unroll
            for (int nt = 0; nt < 4; nt++) {
                unsigned nib = (unsigned)(mk >> (nt * 16 + quad * 4));
#pragma unroll
                for (int r = 0; r < 4; r++) {
                    int bp = nt * 16 + quad * 4 + r;
                    bool ok = ((nib >> r) & 1u) && (bp <= limit);
                    float v = ok ? sc[nt][r] : -INFINITY;
                    p[nt][r] = __builtin_exp2f(__builtin_fmaf(v, scale2, -C2));
                }
            }
        }
        lpart += ((p[0][0] + p[0][1]) + (p[0][2] + p[0][3])) +
                 ((p[1][0] + p[1][1]) + (p[1][2] + p[1][3])) +
                 ((p[2][0] + p[2][1]) + (p[2][2] + p[2][3])) +
                 ((p[3][0] + p[3][1]) + (p[3][2] + p[3][3]));

        // ---- T12: pack to bf16 and redistribute quads in-register.
        unsigned A0, A1, B0, B1, C0, C1, E0, E1;
        asm("v_cvt_pk_bf16_f32 %0, %1, %2" : "=v"(A0) : "v"(p[0][0]), "v"(p[0][1]));
        asm("v_cvt_pk_bf16_f32 %0, %1, %2" : "=v"(A1) : "v"(p[0][2]), "v"(p[0][3]));
        asm("v_cvt_pk_bf16_f32 %0, %1, %2" : "=v"(B0) : "v"(p[1][0]), "v"(p[1][1]));
        asm("v_cvt_pk_bf16_f32 %0, %1, %2" : "=v"(B1) : "v"(p[1][2]), "v"(p[1][3]));
        asm("v_cvt_pk_bf16_f32 %0, %1, %2" : "=v"(C0) : "v"(p[2][0]), "v"(p[2][1]));
        asm("v_cvt_pk_bf16_f32 %0, %1, %2" : "=v"(C1) : "v"(p[2][2]), "v"(p[2][3]));
        asm("v_cvt_pk_bf16_f32 %0, %1, %2" : "=v"(E0) : "v"(p[3][0]), "v"(p[3][1]));
        asm("v_cvt_pk_bf16_f32 %0, %1, %2" : "=v"(E1) : "v"(p[3][2]), "v"(p[3][3]));
        asm("v_permlane32_swap_b32 %0, %1" : "+v"(A0), "+v"(B0));
        asm("v_permlane16_swap_b32 %0, %1" : "+v"(A0), "+v"(B0));  // A0=D0, B0=D2
        asm("v_permlane32_swap_b32 %0, %1" : "+v"(A1), "+v"(B1));
        asm("v_permlane16_swap_b32 %0, %1" : "+v"(A1), "+v"(B1));  // A1=D1, B1=D3
        asm("v_permlane32_swap_b32 %0, %1" : "+v"(C0), "+v"(E0));
        asm("v_permlane16_swap_b32 %0, %1" : "+v"(C0), "+v"(E0));
        asm("v_permlane32_swap_b32 %0, %1" : "+v"(C1), "+v"(E1));
        asm("v_permlane16_swap_b32 %0, %1" : "+v"(C1), "+v"(E1));
        short8 pf0 = __builtin_bit_cast(short8, (uint4v){A0, A1, B0, B1});
        short8 pf1 = __builtin_bit_cast(short8, (uint4v){C0, C1, E0, E1});

        __builtin_amdgcn_s_setprio(1);
#pragma unroll
        for (int dt = 0; dt < 4; dt++)
            o[dt] = __builtin_amdgcn_mfma_f32_16x16x32_bf16(pf0, vf0a[dt], o[dt], 0, 0, 0);
#pragma unroll
        for (int dt = 4; dt < 8; dt++) {
            short8 vf0 = *(const short8*)(&Vs[dt * 16 + l16][quad * 8]);
            o[dt] = __builtin_amdgcn_mfma_f32_16x16x32_bf16(pf0, vf0, o[dt], 0, 0, 0);
        }
#pragma unroll
        for (int dt = 0; dt < 8; dt++) {
            short8 vf1 = *(const short8*)(&Vs[dt * 16 + l16][32 + quad * 8]);
            o[dt] = __builtin_amdgcn_mfma_f32_16x16x32_bf16(pf1, vf1, o[dt], 0, 0, 0);
        }
        __builtin_amdgcn_s_setprio(0);
    }
    // epilogue: full row-sum for q-row l16, then redistribute to output rows.
    float l = lpart;
    l += __shfl_xor(l, 16, 64);
    l += __shfl_xor(l, 32, 64);   // every lane: sum for q-row l16
    float invq[4];
#pragma unroll
    for (int r = 0; r < 4; r++) {
        float lr = __shfl(l, quad * 4 + r, 16);   // sum for q-row quad*4+r
        invq[r] = lr > 0.f ? 1.f / lr : 0.f;
    }
    size_t obase = (size_t)(b * SEQ + q_row0) * HIDDEN + h * HD;
#pragma unroll
    for (int dt = 0; dt < 8; dt++)
#pragma unroll
        for (int r = 0; r < 4; r++)
            attn[obase + (size_t)(quad * 4 + r) * HIDDEN + dt * 16 + l16] =
                f2bf(o[dt][r] * invq[r]);
}

extern "C" void kernel_launch(void* const* d_in, const int* in_sizes, int n_in,
                              void* d_out, int out_size, void* d_ws, size_t ws_size,
                              hipStream_t stream) {
    const float* hidden = (const float*)d_in[0];
    const int* amask   = (const int*)d_in[1];
    const float* Wq = (const float*)d_in[2];
    const float* bq = (const float*)d_in[3];
    const float* Wk = (const float*)d_in[4];
    const float* bk = (const float*)d_in[5];
    const float* Wv = (const float*)d_in[6];
    const float* bv = (const float*)d_in[7];
    const float* Wo = (const float*)d_in[8];
    const float* bo = (const float*)d_in[9];
    float* out = (float*)d_out;

    // workspace layout (~84 MB)
    char* ws = (char*)d_ws;
    u16* xb     = (u16*)ws;  ws += (size_t)MROWS * HIDDEN * 2;        // 16.8 MB
    u16* wqkvT  = (u16*)ws;  ws += (size_t)QKV_N * HIDDEN * 2;       // 12.6 MB
    u16* woT    = (u16*)ws;  ws += (size_t)HIDDEN * HIDDEN * 2;      // 8.4 MB
    float* bqkv = (float*)ws; ws += (size_t)QKV_N * 4;               // 12 KB
    u64* mpk    = (u64*)ws;  ws += (size_t)(MROWS / 64) * 8;         // 512 B
    u16* qkv    = (u16*)ws;  ws += (size_t)MROWS * QKV_N * 2;        // 25.2 MB
    u16* vt     = (u16*)ws;  ws += (size_t)BATCH * NKV * HD * SEQ * 2; // 4.2 MB
    u16* attn   = (u16*)ws;  ws += (size_t)MROWS * HIDDEN * 2;       // 16.8 MB

    // 1. fused prep (convert + 4 transposes + bias + mask) -- one dispatch
    prep<<<dim3(PREP_TOTAL), dim3(256), 0, stream>>>(
        hidden, xb, Wq, Wk, Wv, Wo, wqkvT, woT, bq, bk, bv, bqkv, amask, mpk);

    // 2. fused QKV projection (128x256 2-phase, 384 blocks)
    gemm_bf16_128x256<true><<<dim3(QKV_N / 256, MROWS / 128), dim3(512), 0, stream>>>(
        xb, wqkvT, bqkv, qkv, MROWS, QKV_N, HIDDEN);

    // 3. V^T (vectorized 64x64 transpose)
    vt_from_qkv<<<dim3(SEQ / 64, HD / 64, BATCH * NKV), dim3(256), 0, stream>>>(qkv, vt);

    // 4. attention (128 q rows per block, 8 waves x 16 rows, complementary pairing)
    flash_attn<<<dim3(SEQ / 128, NH, BATCH), dim3(512), 0, stream>>>(qkv, vt, mpk, attn);

    // 5. output projection (128x256 2-phase, 100% fill, fp32 out)
    gemm_bf16_128x256<false><<<dim3(HIDDEN / 256, MROWS / 128), dim3(512), 0, stream>>>(
        attn, woT, bo, out, MROWS, HIDDEN, HIDDEN);
}

// Round 10
// 278.198 us; speedup vs baseline: 1.0596x; 1.0596x over previous
//
#include <hip/hip_runtime.h>
#include <hip/hip_bf16.h>

// CausalSelfAttention on MI355X (gfx950).
// B=2, S=2048, HIDDEN=2048, H=16 heads, D=128, Hkv=4 (GQA groups=4).
// Round 18: single-variable recovery. R17 verdict: QKV on the 2-phase 128x256
//   kernel regressed ~18us (effective fill unchanged at 75% -- 384 blocks @
//   1/CU = 1.5 rounds -- while per-CU schedule quality dropped; the 2-phase
//   kernel's Wo win was purely the 50->100% fill lever). Restore QKV to the
//   256^2 8-phase kernel (R16 exact). Keep Wo on 128x256 2-phase (100% fill)
//   and keep R17's vectorized vt (this round = clean A/B of vt vs R16).
//
// MFMA layouts (HW-verified per guide m89/m91/m120):
//   A frag: A[m=lane&15][k=(lane>>4)*8 + j], j=0..7  (16B contiguous in K)
//   B frag: B^T stored [n][k], same addressing as A
//   C/D   : col=lane&15, row=(lane>>4)*4 + reg

typedef unsigned short u16;
typedef unsigned long long u64;
typedef __attribute__((ext_vector_type(8))) short short8;   // 8 x bf16 (4 VGPRs)
typedef __attribute__((ext_vector_type(4))) float f32x4;
typedef __attribute__((ext_vector_type(4))) unsigned uint4v;

#define BATCH 2
#define SEQ 2048
#define HIDDEN 2048
#define NH 16
#define NKV 4
#define HD 128
#define QKV_N 3072   // 2048 q + 512 k + 512 v
#define MROWS 4096   // BATCH*SEQ

__device__ inline u16 f2bf(float f) {
    __hip_bfloat16 h = __float2bfloat16(f);
    return __builtin_bit_cast(u16, h);
}

// async global->LDS, 16B per lane; lds base must be wave-uniform (HW adds lane*16)
__device__ inline void async_copy16(const u16* g, u16* lds_base) {
    __builtin_amdgcn_global_load_lds(
        (const __attribute__((address_space(1))) void*)g,
        (__attribute__((address_space(3))) void*)lds_base, 16, 0, 0);
}

// ---------------- fused prep: convert + 4 transposes + bias + mask ----------------
#define PREP_CONV   4096
#define PREP_WQ     (PREP_CONV + 1024)
#define PREP_WK     (PREP_WQ + 256)
#define PREP_WV     (PREP_WK + 256)
#define PREP_WO     (PREP_WV + 1024)
#define PREP_BIAS   (PREP_WO + 12)
#define PREP_TOTAL  (PREP_BIAS + 1)

// src[K=2048][N] fp32 -> dst[N][2048] bf16, one 64x64 tile per block.
__device__ inline void prep_transpose64(const float* __restrict__ src, u16* __restrict__ dst,
                                        int N, int sub, float (*tl)[69]) {
    int nx = N >> 6;
    int bx = sub % nx, by = sub / nx;
    int n0 = bx * 64, k0 = by * 64;
    int t = threadIdx.x;
    int rr = t >> 4, cc = (t & 15) * 4;       // read rows k0+rr+16j, cols n0+cc..+3
#pragma unroll
    for (int j = 0; j < 4; ++j) {
        float4 v = *(const float4*)(src + (size_t)(k0 + rr + 16 * j) * N + n0 + cc);
        int k = rr + 16 * j;
        tl[cc + 0][k] = v.x;
        tl[cc + 1][k] = v.y;
        tl[cc + 2][k] = v.z;
        tl[cc + 3][k] = v.w;
    }
    __syncthreads();
    int n = t >> 2;                            // write dst row n0+n, 2 chunks of 8 k
#pragma unroll
    for (int j = 0; j < 2; ++j) {
        int kk = (t & 3) * 8 + 32 * j;
        short8 o8;
#pragma unroll
        for (int i = 0; i < 8; ++i) o8[i] = (short)f2bf(tl[n][kk + i]);
        *(short8*)(dst + (size_t)(n0 + n) * HIDDEN + k0 + kk) = o8;
    }
}

__global__ __launch_bounds__(256)
void prep(const float* __restrict__ hidden, u16* __restrict__ xb,
          const float* __restrict__ Wq, const float* __restrict__ Wk,
          const float* __restrict__ Wv, const float* __restrict__ Wo,
          u16* __restrict__ wqkvT, u16* __restrict__ woT,
          const float* __restrict__ bq, const float* __restrict__ bk,
          const float* __restrict__ bv, float* __restrict__ bqkv,
          const int* __restrict__ am, u64* __restrict__ mp) {
    __shared__ float tl[64][69];
    int bid = blockIdx.x;
    if (bid < PREP_CONV) {
        int i = (bid * 256 + threadIdx.x) * 8;
        float4 v0 = *(const float4*)(hidden + i);
        float4 v1 = *(const float4*)(hidden + i + 4);
        short8 o8;
        o8[0] = (short)f2bf(v0.x); o8[1] = (short)f2bf(v0.y);
        o8[2] = (short)f2bf(v0.z); o8[3] = (short)f2bf(v0.w);
        o8[4] = (short)f2bf(v1.x); o8[5] = (short)f2bf(v1.y);
        o8[6] = (short)f2bf(v1.z); o8[7] = (short)f2bf(v1.w);
        *(short8*)(xb + i) = o8;
    } else if (bid < PREP_WQ) {
        prep_transpose64(Wq, wqkvT, 2048, bid - PREP_CONV, tl);
    } else if (bid < PREP_WK) {
        prep_transpose64(Wk, wqkvT + (size_t)2048 * HIDDEN, 512, bid - PREP_WQ, tl);
    } else if (bid < PREP_WV) {
        prep_transpose64(Wv, wqkvT + (size_t)2560 * HIDDEN, 512, bid - PREP_WK, tl);
    } else if (bid < PREP_WO) {
        prep_transpose64(Wo, woT, 2048, bid - PREP_WV, tl);
    } else if (bid < PREP_BIAS) {
        int i = (bid - PREP_WO) * 256 + threadIdx.x;
        if (i < QKV_N)
            bqkv[i] = (i < 2048) ? bq[i] : ((i < 2560) ? bk[i - 2048] : bv[i - 2560]);
    } else {
        int i = threadIdx.x;   // word index, 64 total
        if (i < BATCH * SEQ / 64) {
            const int* a = am + i * 64;
            u64 m = 0;
#pragma unroll
            for (int j = 0; j < 64; j += 4) {
                int4 v = *(const int4*)(a + j);
                m |= ((u64)(v.x != 0) << j) | ((u64)(v.y != 0) << (j + 1)) |
                     ((u64)(v.z != 0) << (j + 2)) | ((u64)(v.w != 0) << (j + 3));
            }
            mp[i] = m;
        }
    }
}

// ---------------- V^T extraction from qkv buffer (vectorized 64x64) ----------------
// (R17 version: short8 16B global on both sides; LDS u16 scatter transpose)
__global__ __launch_bounds__(256)
void vt_from_qkv(const u16* __restrict__ qkv, u16* __restrict__ vt) {
    __shared__ u16 tl[64][72];   // [d][s], row stride 144 B (16B-aligned)
    int b = blockIdx.z >> 2, kvh = blockIdx.z & 3;
    int s0 = blockIdx.x * 64, d0 = blockIdx.y * 64;
    int t = threadIdx.x;
    int sr = t >> 2, ch = t & 3;   // row within tile, chunk index
#pragma unroll
    for (int j = 0; j < 2; ++j) {
        int dd = (ch + 4 * j) * 8;
        short8 v = *(const short8*)(qkv + (size_t)(b * SEQ + s0 + sr) * QKV_N +
                                    2560 + kvh * HD + d0 + dd);
#pragma unroll
        for (int i = 0; i < 8; ++i) tl[dd + i][sr] = (u16)v[i];
    }
    __syncthreads();
#pragma unroll
    for (int j = 0; j < 2; ++j) {
        int ss = (ch + 4 * j) * 8;
        short8 o;
#pragma unroll
        for (int i = 0; i < 8; ++i) o[i] = (short)tl[sr][ss + i];
        *(short8*)(vt + (size_t)((b * NKV + kvh) * HD + d0 + sr) * SEQ + s0 + ss) = o;
    }
}

// ---------------- bf16 GEMM, 256^2 8-phase counted-vmcnt (QKV projection) ----------
// (byte-identical to R13/R14/R16; ledger in comments)
template <bool OUT_BF16>
__global__ __launch_bounds__(512, 2)
void gemm_bf16_256(const u16* __restrict__ A, const u16* __restrict__ BT,
                   const float* __restrict__ bias, void* __restrict__ outp,
                   int M, int N, int K) {
    __shared__ __align__(16) u16 smem[2][2][256][64];   // [buf][A=0/B=1][row][col] 128 KiB
    const int t = threadIdx.x, w = t >> 6, lane = t & 63;
    const int quad = lane >> 4, l16 = lane & 15;
    const int wm = w >> 2, wn = w & 3;
    const int bm0 = blockIdx.y * 256, bn0 = blockIdx.x * 256;
    const int lrow = lane >> 3;            // staging: row within 8-row group
    const int lchk = (lane & 7) ^ lrow;    // staging: swizzled source chunk
    const int NT = K >> 6;

    f32x4 acc[8][4];
#pragma unroll
    for (int i = 0; i < 8; i++)
#pragma unroll
        for (int j = 0; j < 4; j++) acc[i][j] = (f32x4){0.f, 0.f, 0.f, 0.f};

    const u16* gA = A + (size_t)bm0 * K;
    const u16* gB = BT + (size_t)bn0 * K;

    auto stage = [&](int buf, int op, int h, int k0) {
        const u16* gb = op ? gB : gA;
#pragma unroll
        for (int l = 0; l < 2; ++l) {
            int rb = h * 128 + w * 16 + l * 8;             // wave-uniform row base
            async_copy16(gb + (size_t)(rb + lrow) * K + k0 + lchk * 8,
                         &smem[buf][op][rb][0]);
        }
    };
    auto readA = [&](short8 (&aq)[4][2], int buf, int mh) {
#pragma unroll
        for (int mt = 0; mt < 4; ++mt) {
            int row = mh * 128 + mt * 32 + wm * 16 + l16;
            int swz = row & 7;
#pragma unroll
            for (int kk = 0; kk < 2; ++kk) {
                int chunk = ((kk << 2) | quad) ^ swz;
                aq[mt][kk] = *(const short8*)(&smem[buf][0][row][chunk << 3]);
            }
        }
    };
    auto readB = [&](short8 (&bq)[2][2], int buf, int nh) {
#pragma unroll
        for (int nt = 0; nt < 2; ++nt) {
            int row = nh * 128 + nt * 64 + wn * 16 + l16;
            int swz = row & 7;
#pragma unroll
            for (int kk = 0; kk < 2; ++kk) {
                int chunk = ((kk << 2) | quad) ^ swz;
                bq[nt][kk] = *(const short8*)(&smem[buf][1][row][chunk << 3]);
            }
        }
    };
    auto mmaQ = [&](short8 (&aq)[4][2], short8 (&bq)[2][2], int mh, int nh) {
        __builtin_amdgcn_s_setprio(1);
#pragma unroll
        for (int mt = 0; mt < 4; ++mt)
#pragma unroll
            for (int nt = 0; nt < 2; ++nt)
#pragma unroll
                for (int kk = 0; kk < 2; ++kk)
                    acc[mh * 4 + mt][nh * 2 + nt] = __builtin_amdgcn_mfma_f32_16x16x32_bf16(
                        aq[mt][kk], bq[nt][kk], acc[mh * 4 + mt][nh * 2 + nt], 0, 0, 0);
        __builtin_amdgcn_s_setprio(0);
    };

    // prologue: stage tile 0 -> buf 0 in order Ah0, Bh0, Bh1, Ah1
    stage(0, 0, 0, 0); stage(0, 1, 0, 0); stage(0, 1, 1, 0); stage(0, 0, 1, 0);
    asm volatile("s_waitcnt vmcnt(4)" ::: "memory");
    __builtin_amdgcn_s_barrier();

    short8 aq[4][2], b0[2][2], b1[2][2];
    for (int tt = 0; tt < NT - 1; ++tt) {
        const int cur = tt & 1, nxt = cur ^ 1, k1 = (tt + 1) << 6;
        // ph0: quadrant (0,0)
        readA(aq, cur, 0); readB(b0, cur, 0);
        stage(nxt, 0, 0, k1);                  // Ah0(t+1)
        mmaQ(aq, b0, 0, 0);
        asm volatile("s_waitcnt vmcnt(4)" ::: "memory");
        __builtin_amdgcn_s_barrier();
        // ph1: quadrant (0,1)
        readB(b1, cur, 1);
        stage(nxt, 1, 0, k1);                  // Bh0(t+1)
        mmaQ(aq, b1, 0, 1);
        asm volatile("s_waitcnt vmcnt(4)" ::: "memory");
        __builtin_amdgcn_s_barrier();
        // ph2: quadrant (1,1)
        readA(aq, cur, 1);
        stage(nxt, 1, 1, k1);                  // Bh1(t+1)
        mmaQ(aq, b1, 1, 1);
        asm volatile("s_waitcnt vmcnt(6)" ::: "memory");
        __builtin_amdgcn_s_barrier();
        // ph3: quadrant (1,0)
        stage(nxt, 0, 1, k1);                  // Ah1(t+1)
        mmaQ(aq, b0, 1, 0);
        asm volatile("s_waitcnt vmcnt(4)" ::: "memory");
        __builtin_amdgcn_s_barrier();
    }
    // peeled last tile
    asm volatile("s_waitcnt vmcnt(0)" ::: "memory");
    __builtin_amdgcn_s_barrier();
    {
        const int cur = (NT - 1) & 1;
        readA(aq, cur, 0); readB(b0, cur, 0);
        mmaQ(aq, b0, 0, 0);
        readB(b1, cur, 1);
        mmaQ(aq, b1, 0, 1);
        readA(aq, cur, 1);
        mmaQ(aq, b1, 1, 1);
        mmaQ(aq, b0, 1, 0);
    }

    // epilogue
#pragma unroll
    for (int nt = 0; nt < 4; ++nt) {
        int col = bn0 + nt * 64 + wn * 16 + l16;
        float bcol = bias[col];
#pragma unroll
        for (int mt = 0; mt < 8; ++mt) {
#pragma unroll
            for (int r = 0; r < 4; ++r) {
                int row = bm0 + mt * 32 + wm * 16 + quad * 4 + r;
                float v = acc[mt][nt][r] + bcol;
                if constexpr (OUT_BF16)
                    ((u16*)outp)[(size_t)row * N + col] = f2bf(v);
                else
                    ((float*)outp)[(size_t)row * N + col] = v;
            }
        }
    }
}

// ---------------- bf16 GEMM, 128x256 2-phase counted-vmcnt (Wo projection) -------
// (identical to R15/R16; 256 blocks = 100% CU fill; ledger in comments)
__global__ __launch_bounds__(512, 2)
void gemm_bf16_128x256(const u16* __restrict__ A, const u16* __restrict__ BT,
                       const float* __restrict__ bias, float* __restrict__ outp,
                       int M, int N, int K) {
    __shared__ __align__(16) u16 sA[2][128][64];   // 32 KiB
    __shared__ __align__(16) u16 sB[2][256][64];   // 64 KiB
    const int t = threadIdx.x, w = t >> 6, lane = t & 63;
    const int quad = lane >> 4, l16 = lane & 15;
    const int wm = w >> 2, wn = w & 3;
    const int bm0 = blockIdx.y * 128, bn0 = blockIdx.x * 256;
    const int lrow = lane >> 3;
    const int lchk = (lane & 7) ^ lrow;
    const int NT = K >> 6;

    f32x4 acc[4][4];
#pragma unroll
    for (int i = 0; i < 4; i++)
#pragma unroll
        for (int j = 0; j < 4; j++) acc[i][j] = (f32x4){0.f, 0.f, 0.f, 0.f};

    const u16* gA = A + (size_t)bm0 * K;
    const u16* gB = BT + (size_t)bn0 * K;

    auto stageA = [&](int buf, int k0) {
#pragma unroll
        for (int l = 0; l < 2; ++l) {
            int rb = w * 16 + l * 8;
            async_copy16(gA + (size_t)(rb + lrow) * K + k0 + lchk * 8, &sA[buf][rb][0]);
        }
    };
    auto stageB = [&](int buf, int h, int k0) {
#pragma unroll
        for (int l = 0; l < 2; ++l) {
            int rb = h * 128 + w * 16 + l * 8;
            async_copy16(gB + (size_t)(rb + lrow) * K + k0 + lchk * 8, &sB[buf][rb][0]);
        }
    };
    auto readA = [&](short8 (&aq)[4][2], int buf) {
#pragma unroll
        for (int mt = 0; mt < 4; ++mt) {
            int row = wm * 64 + mt * 16 + l16;
            int swz = row & 7;
#pragma unroll
            for (int kk = 0; kk < 2; ++kk) {
                int chunk = ((kk << 2) | quad) ^ swz;
                aq[mt][kk] = *(const short8*)(&sA[buf][row][chunk << 3]);
            }
        }
    };
    auto readB = [&](short8 (&bq)[2][2], int buf, int nh) {
#pragma unroll
        for (int nt = 0; nt < 2; ++nt) {
            int row = nh * 128 + nt * 64 + wn * 16 + l16;
            int swz = row & 7;
#pragma unroll
            for (int kk = 0; kk < 2; ++kk) {
                int chunk = ((kk << 2) | quad) ^ swz;
                bq[nt][kk] = *(const short8*)(&sB[buf][row][chunk << 3]);
            }
        }
    };
    auto mmaH = [&](short8 (&aq)[4][2], short8 (&bq)[2][2], int nh) {
        __builtin_amdgcn_s_setprio(1);
#pragma unroll
        for (int mt = 0; mt < 4; ++mt)
#pragma unroll
            for (int nt = 0; nt < 2; ++nt)
#pragma unroll
                for (int kk = 0; kk < 2; ++kk)
                    acc[mt][nh * 2 + nt] = __builtin_amdgcn_mfma_f32_16x16x32_bf16(
                        aq[mt][kk], bq[nt][kk], acc[mt][nh * 2 + nt], 0, 0, 0);
        __builtin_amdgcn_s_setprio(0);
    };

    // prologue: A(0), Bh0(0), Bh1(0)
    stageA(0, 0); stageB(0, 0, 0); stageB(0, 1, 0);
    asm volatile("s_waitcnt vmcnt(2)" ::: "memory");
    __builtin_amdgcn_s_barrier();

    short8 aq[4][2], b0[2][2], b1[2][2];
    for (int tt = 0; tt < NT - 1; ++tt) {
        const int cur = tt & 1, nxt = cur ^ 1, k1 = (tt + 1) << 6;
        // ph0: B-half 0
        readA(aq, cur); readB(b0, cur, 0);
        stageA(nxt, k1); stageB(nxt, 0, k1);
        mmaH(aq, b0, 0);
        asm volatile("s_waitcnt vmcnt(4)" ::: "memory");
        __builtin_amdgcn_s_barrier();
        // ph1: B-half 1
        readB(b1, cur, 1);
        stageB(nxt, 1, k1);
        mmaH(aq, b1, 1);
        asm volatile("s_waitcnt vmcnt(2)" ::: "memory");
        __builtin_amdgcn_s_barrier();
    }
    // peeled last tile
    asm volatile("s_waitcnt vmcnt(0)" ::: "memory");
    __builtin_amdgcn_s_barrier();
    {
        const int cur = (NT - 1) & 1;
        readA(aq, cur); readB(b0, cur, 0);
        mmaH(aq, b0, 0);
        readB(b1, cur, 1);
        mmaH(aq, b1, 1);
    }

    // epilogue (fp32 out + bias)
#pragma unroll
    for (int j = 0; j < 4; ++j) {
        int col = bn0 + j * 64 + wn * 16 + l16;
        float bcol = bias[col];
#pragma unroll
        for (int mt = 0; mt < 4; ++mt) {
#pragma unroll
            for (int r = 0; r < 4; ++r) {
                int row = bm0 + wm * 64 + mt * 16 + quad * 4 + r;
                outp[(size_t)row * N + col] = acc[mt][j][r] + bcol;
            }
        }
    }
}

// ---------------- flash attention (causal, GQA), fixed-shift softmax --------
// (byte-identical to R14/R16: padded Ks[64][136]/Vs[128][72]; mask fast path; T12)
__global__ __launch_bounds__(512, 4)
void flash_attn(const u16* __restrict__ qkv, const u16* __restrict__ vt,
                const u64* __restrict__ mp, u16* __restrict__ attn) {
    __shared__ __align__(16) u16 Ks[64][136];   // 128 + 8 pad (natural key order)
    __shared__ __align__(16) u16 Vs[128][72];   // 64 + 8 pad
    int t = threadIdx.x, w = t >> 6, lane = t & 63, quad = lane >> 4, l16 = lane & 15;
    int bx = blockIdx.x, b = blockIdx.z;
    int qt = b ? ((int)gridDim.x - 1 - bx) : bx;    // complementary pairing
    int h = blockIdx.y, kvh = h >> 2;
    int q_row0 = qt * 128 + w * 16;

    const u16* qrow = qkv + (size_t)(b * SEQ + q_row0 + l16) * QKV_N + h * HD;
    short8 qf[4];
#pragma unroll
    for (int c = 0; c < 4; c++) qf[c] = *(const short8*)(qrow + c * 32 + quad * 8);

    f32x4 o[8];
#pragma unroll
    for (int dt = 0; dt < 8; dt++) o[dt] = (f32x4){0.f, 0.f, 0.f, 0.f};
    float lpart = 0.f;   // per-lane partial row-sum for q-row l16

    const float scale2 = 0.12751743f;   // (1/sqrt(128)) * log2(e)
    const float C2 = 14.4269504f;       // 10 * log2(e)

    const u16* kgb = qkv + (size_t)(b * SEQ) * QKV_N + 2048 + kvh * HD;
    const u16* vgb = vt + (size_t)((b * NKV + kvh) * HD) * SEQ;
    const u64* mpb = mp + b * (SEQ / 64);

    int kr = t >> 4, kc = (t & 15) * 8;   // K: 16 chunks per 128-col row
    int vr = t >> 3, vc = (t & 7) * 8;    // V: 8 chunks per 64-col row
    int kb_end = (qt + 1) * 128;

    short8 k0p, k1p, v0p, v1p;
    {
        k0p = *(const short8*)(kgb + (size_t)kr * QKV_N + kc);
        k1p = *(const short8*)(kgb + (size_t)(kr + 32) * QKV_N + kc);
        v0p = *(const short8*)(vgb + (size_t)vr * SEQ + vc);
        v1p = *(const short8*)(vgb + (size_t)(vr + 64) * SEQ + vc);
    }

    for (int kb = 0; kb < kb_end; kb += 64) {
        __syncthreads();  // previous iter's LDS reads done
        *(short8*)(&Ks[kr][kc]) = k0p;
        *(short8*)(&Ks[kr + 32][kc]) = k1p;
        *(short8*)(&Vs[vr][vc]) = v0p;
        *(short8*)(&Vs[vr + 64][vc]) = v1p;
        __syncthreads();
        if (kb + 64 < kb_end) {  // prefetch next tile during compute (T14 issue-early)
            const u16* kg = kgb + (size_t)(kb + 64) * QKV_N;
            const u16* vg = vgb + kb + 64;
            k0p = *(const short8*)(kg + (size_t)kr * QKV_N + kc);
            k1p = *(const short8*)(kg + (size_t)(kr + 32) * QKV_N + kc);
            v0p = *(const short8*)(vg + (size_t)vr * SEQ + vc);
            v1p = *(const short8*)(vg + (size_t)(vr + 64) * SEQ + vc);
        }
        if (kb > q_row0 + 15) continue;  // wave-uniform: no keys for this wave's rows

        u64 mk = mpb[kb >> 6];   // wave-uniform mask bits for keys kb..kb+63

        // ---- scores (swapped): sc[nt][r] = S[key=kb+nt*16+quad*4+r][qrow=l16]
        f32x4 sc[4];
#pragma unroll
        for (int nt = 0; nt < 4; nt++) sc[nt] = (f32x4){0.f, 0.f, 0.f, 0.f};
        __builtin_amdgcn_s_setprio(1);
#pragma unroll
        for (int c = 0; c < 4; c++) {
#pragma unroll
            for (int nt = 0; nt < 4; nt++) {
                short8 kf = *(const short8*)(&Ks[nt * 16 + l16][c * 32 + quad * 8]);
                sc[nt] = __builtin_amdgcn_mfma_f32_16x16x32_bf16(kf, qf[c], sc[nt], 0, 0, 0);
            }
        }
        __builtin_amdgcn_s_setprio(0);

        // early V fragments (keys 0..31, dims 0..63): independent of softmax
        short8 vf0a[4];
#pragma unroll
        for (int dt = 0; dt < 4; dt++)
            vf0a[dt] = *(const short8*)(&Vs[dt * 16 + l16][quad * 8]);

        // ---- fixed-shift exp; fast path for fully-valid tiles (wave-uniform)
        float p[4][4];
        if (mk == ~0ull && kb + 63 <= q_row0) {
#pragma unroll
            for (int nt = 0; nt < 4; nt++)
#pragma unroll
                for (int r = 0; r < 4; r++)
                    p[nt][r] = __builtin_exp2f(__builtin_fmaf(sc[nt][r], scale2, -C2));
        } else {
            int limit = q_row0 + l16 - kb;   // keep iff bp <= limit (causal)
#pragma unroll
            for (int nt = 0; nt < 4; nt++) {
                unsigned nib = (unsigned)(mk >> (nt * 16 + quad * 4));
#pragma unroll
                for (int r = 0; r < 4; r++) {
                    int bp = nt * 16 + quad * 4 + r;
                    bool ok = ((nib >> r) & 1u) && (bp <= limit);
                    float v = ok ? sc[nt][r] : -INFINITY;
                    p[nt][r] = __builtin_exp2f(__builtin_fmaf(v, scale2, -C2));
                }
            }
        }
        lpart += ((p[0][0] + p[0][1]) + (p[0][2] + p[0][3])) +
                 ((p[1][0] + p[1][1]) + (p[1][2] + p[1][3])) +
                 ((p[2][0] + p[2][1]) + (p[2][2] + p[2][3])) +
                 ((p[3][0] + p[3][1]) + (p[3][2] + p[3][3]));

        // ---- T12: pack to bf16 and redistribute quads in-register.
        unsigned A0, A1, B0, B1, C0, C1, E0, E1;
        asm("v_cvt_pk_bf16_f32 %0, %1, %2" : "=v"(A0) : "v"(p[0][0]), "v"(p[0][1]));
        asm("v_cvt_pk_bf16_f32 %0, %1, %2" : "=v"(A1) : "v"(p[0][2]), "v"(p[0][3]));
        asm("v_cvt_pk_bf16_f32 %0, %1, %2" : "=v"(B0) : "v"(p[1][0]), "v"(p[1][1]));
        asm("v_cvt_pk_bf16_f32 %0, %1, %2" : "=v"(B1) : "v"(p[1][2]), "v"(p[1][3]));
        asm("v_cvt_pk_bf16_f32 %0, %1, %2" : "=v"(C0) : "v"(p[2][0]), "v"(p[2][1]));
        asm("v_cvt_pk_bf16_f32 %0, %1, %2" : "=v"(C1) : "v"(p[2][2]), "v"(p[2][3]));
        asm("v_cvt_pk_bf16_f32 %0, %1, %2" : "=v"(E0) : "v"(p[3][0]), "v"(p[3][1]));
        asm("v_cvt_pk_bf16_f32 %0, %1, %2" : "=v"(E1) : "v"(p[3][2]), "v"(p[3][3]));
        asm("v_permlane32_swap_b32 %0, %1" : "+v"(A0), "+v"(B0));
        asm("v_permlane16_swap_b32 %0, %1" : "+v"(A0), "+v"(B0));  // A0=D0, B0=D2
        asm("v_permlane32_swap_b32 %0, %1" : "+v"(A1), "+v"(B1));
        asm("v_permlane16_swap_b32 %0, %1" : "+v"(A1), "+v"(B1));  // A1=D1, B1=D3
        asm("v_permlane32_swap_b32 %0, %1" : "+v"(C0), "+v"(E0));
        asm("v_permlane16_swap_b32 %0, %1" : "+v"(C0), "+v"(E0));
        asm("v_permlane32_swap_b32 %0, %1" : "+v"(C1), "+v"(E1));
        asm("v_permlane16_swap_b32 %0, %1" : "+v"(C1), "+v"(E1));
        short8 pf0 = __builtin_bit_cast(short8, (uint4v){A0, A1, B0, B1});
        short8 pf1 = __builtin_bit_cast(short8, (uint4v){C0, C1, E0, E1});

        __builtin_amdgcn_s_setprio(1);
#pragma unroll
        for (int dt = 0; dt < 4; dt++)
            o[dt] = __builtin_amdgcn_mfma_f32_16x16x32_bf16(pf0, vf0a[dt], o[dt], 0, 0, 0);
#pragma unroll
        for (int dt = 4; dt < 8; dt++) {
            short8 vf0 = *(const short8*)(&Vs[dt * 16 + l16][quad * 8]);
            o[dt] = __builtin_amdgcn_mfma_f32_16x16x32_bf16(pf0, vf0, o[dt], 0, 0, 0);
        }
#pragma unroll
        for (int dt = 0; dt < 8; dt++) {
            short8 vf1 = *(const short8*)(&Vs[dt * 16 + l16][32 + quad * 8]);
            o[dt] = __builtin_amdgcn_mfma_f32_16x16x32_bf16(pf1, vf1, o[dt], 0, 0, 0);
        }
        __builtin_amdgcn_s_setprio(0);
    }
    // epilogue: full row-sum for q-row l16, then redistribute to output rows.
    float l = lpart;
    l += __shfl_xor(l, 16, 64);
    l += __shfl_xor(l, 32, 64);   // every lane: sum for q-row l16
    float invq[4];
#pragma unroll
    for (int r = 0; r < 4; r++) {
        float lr = __shfl(l, quad * 4 + r, 16);   // sum for q-row quad*4+r
        invq[r] = lr > 0.f ? 1.f / lr : 0.f;
    }
    size_t obase = (size_t)(b * SEQ + q_row0) * HIDDEN + h * HD;
#pragma unroll
    for (int dt = 0; dt < 8; dt++)
#pragma unroll
        for (int r = 0; r < 4; r++)
            attn[obase + (size_t)(quad * 4 + r) * HIDDEN + dt * 16 + l16] =
                f2bf(o[dt][r] * invq[r]);
}

extern "C" void kernel_launch(void* const* d_in, const int* in_sizes, int n_in,
                              void* d_out, int out_size, void* d_ws, size_t ws_size,
                              hipStream_t stream) {
    const float* hidden = (const float*)d_in[0];
    const int* amask   = (const int*)d_in[1];
    const float* Wq = (const float*)d_in[2];
    const float* bq = (const float*)d_in[3];
    const float* Wk = (const float*)d_in[4];
    const float* bk = (const float*)d_in[5];
    const float* Wv = (const float*)d_in[6];
    const float* bv = (const float*)d_in[7];
    const float* Wo = (const float*)d_in[8];
    const float* bo = (const float*)d_in[9];
    float* out = (float*)d_out;

    // workspace layout (~84 MB)
    char* ws = (char*)d_ws;
    u16* xb     = (u16*)ws;  ws += (size_t)MROWS * HIDDEN * 2;        // 16.8 MB
    u16* wqkvT  = (u16*)ws;  ws += (size_t)QKV_N * HIDDEN * 2;       // 12.6 MB
    u16* woT    = (u16*)ws;  ws += (size_t)HIDDEN * HIDDEN * 2;      // 8.4 MB
    float* bqkv = (float*)ws; ws += (size_t)QKV_N * 4;               // 12 KB
    u64* mpk    = (u64*)ws;  ws += (size_t)(MROWS / 64) * 8;         // 512 B
    u16* qkv    = (u16*)ws;  ws += (size_t)MROWS * QKV_N * 2;        // 25.2 MB
    u16* vt     = (u16*)ws;  ws += (size_t)BATCH * NKV * HD * SEQ * 2; // 4.2 MB
    u16* attn   = (u16*)ws;  ws += (size_t)MROWS * HIDDEN * 2;       // 16.8 MB

    // 1. fused prep (convert + 4 transposes + bias + mask) -- one dispatch
    prep<<<dim3(PREP_TOTAL), dim3(256), 0, stream>>>(
        hidden, xb, Wq, Wk, Wv, Wo, wqkvT, woT, bq, bk, bv, bqkv, amask, mpk);

    // 2. fused QKV projection (256^2 8-phase, restored)
    gemm_bf16_256<true><<<dim3(QKV_N / 256, MROWS / 256), dim3(512), 0, stream>>>(
        xb, wqkvT, bqkv, qkv, MROWS, QKV_N, HIDDEN);

    // 3. V^T (vectorized 64x64 transpose)
    vt_from_qkv<<<dim3(SEQ / 64, HD / 64, BATCH * NKV), dim3(256), 0, stream>>>(qkv, vt);

    // 4. attention (128 q rows per block, 8 waves x 16 rows, complementary pairing)
    flash_attn<<<dim3(SEQ / 128, NH, BATCH), dim3(512), 0, stream>>>(qkv, vt, mpk, attn);

    // 5. output projection (128x256 2-phase, 100% fill, fp32 out)
    gemm_bf16_128x256<<<dim3(HIDDEN / 256, MROWS / 128), dim3(512), 0, stream>>>(
        attn, woT, bo, out, MROWS, HIDDEN, HIDDEN);
}